// Round 13
// baseline (20.876 us; speedup 1.0000x reference)
//
#include <hip/hip_runtime.h>
#include <math.h>

constexpr int TLEN = 512;
constexpr int CDIM = 64;
constexpr int BDIM = 2;

// Phase 1: hkt4[(b*16+c4)*512 + t] = float4-over-c of hk[b,t,c].
// 256 blocks x 256 threads, 4 rows/block.
__global__ __launch_bounds__(256) void hk_kernel(
    const float* __restrict__ x, const float* __restrict__ pos,
    const float* __restrict__ W1, float4* __restrict__ hkt4)
{
    const int tid = threadIdx.x;
    const int r0g = blockIdx.x * 4;
    const int b   = r0g >> 9;
    const int t0  = r0g & (TLEN - 1);

    __shared__ float4 wk_s[64 * 32];          // 32 KiB swizzled Wk
    __shared__ alignas(16) float x1s[4][128];
    __shared__ float hks[CDIM][5];            // +1 pad

    const float4* W1f4 = (const float4*)W1;
    #pragma unroll
    for (int m = tid; m < 64 * 32; m += 256) {
        const int c = m >> 5, e4 = m & 31;
        wk_s[c * 32 + (e4 ^ (c & 31))] = W1f4[c * 64 + e4];
    }
    #pragma unroll
    for (int e = tid; e < 4 * 128; e += 256) {
        const int r4 = e >> 7, d = e & 127;
        const int grow = r0g + r4;
        const int tt = grow & (TLEN - 1);
        x1s[r4][d] = (d < CDIM) ? pos[tt * CDIM + d]
                                : x[grow * CDIM + (d - CDIM)];
    }
    __syncthreads();

    {
        const int sub = tid >> 6, c = tid & 63;
        const float4* xv = (const float4*)x1s[sub];
        const float4* wb = wk_s + c * 32;
        const int sw = c & 31;
        float4 a = make_float4(0.f, 0.f, 0.f, 0.f);
        #pragma unroll
        for (int d4 = 0; d4 < 32; ++d4) {
            const float4 xx = xv[d4];
            const float4 ww = wb[d4 ^ sw];
            a.x = fmaf(xx.x, ww.x, a.x); a.y = fmaf(xx.y, ww.y, a.y);
            a.z = fmaf(xx.z, ww.z, a.z); a.w = fmaf(xx.w, ww.w, a.w);
        }
        hks[c][sub] = (a.x + a.y) + (a.z + a.w);
    }
    __syncthreads();

    if (tid < 64) {
        const int c4 = tid >> 2, tl = tid & 3;
        const float4 v = make_float4(hks[c4 * 4 + 0][tl], hks[c4 * 4 + 1][tl],
                                     hks[c4 * 4 + 2][tl], hks[c4 * 4 + 3][tl]);
        hkt4[(b * 16 + c4) * TLEN + t0 + tl] = v;
    }
}

// Phase 2: 256 blocks x 1024 threads (16 waves/CU = 50% occupancy).
// Block owns 4 rows {p, p+128, 383-p, 511-p}. Half 0 (tid<512) handles rows
// {p, 511-p}, half 1 rows {p+128, 383-p}: each half = 513 j-units (balanced).
// Wave-uniform causal skip; weights staged in LDS (swizzled) as R10.
__global__ __launch_bounds__(1024, 4) void attn_kernel(
    const float* __restrict__ x,  const float* __restrict__ pos,
    const float* __restrict__ W1, const float* __restrict__ b1,
    const float* __restrict__ W2, const float* __restrict__ b2,
    const float* __restrict__ Wv, const float4* __restrict__ hkt4,
    float* __restrict__ out)
{
    const int tid  = threadIdx.x;
    const int idx  = blockIdx.x;              // 0..255
    const int b    = idx & 1;
    const int p    = idx >> 1;                // 0..127
    int r[4];
    r[0] = p; r[1] = p + 128; r[2] = 383 - p; r[3] = 511 - p;

    const int half = tid >> 9;                // 0/1
    const int jj   = tid & 511;               // j column
    const int gw   = (tid >> 6) & 7;          // wave index within half
    const int wg   = tid >> 6;                // global wave index (0..15)
    const int ka   = half ? 1 : 2;            // this half's short row
    const int kb   = half ? 2 : 3;            // long row  (half0: {0,3}, half1: {1,2})
    const int kA   = half ? 1 : 0;
    const int kB   = half ? 2 : 3;

    __shared__ float4 wq_s[64 * 32];          // 32 KiB swizzled Wq
    __shared__ float4 wv_s[64 * 16];          // 16 KiB swizzled Wv
    __shared__ alignas(16) float x1s[4][128];
    __shared__ float hqp[4][CDIM][4];
    __shared__ alignas(16) float hq_sf[4][CDIM];
    __shared__ float4 w24_s[16];
    __shared__ alignas(16) float pS[4][TLEN];
    __shared__ float2 wredm[16];              // per-wave {m_kA, m_kB}
    __shared__ float2 wreds[16];              // per-wave {s_kA, s_kB}
    __shared__ float pvs[4][8][CDIM];
    __shared__ alignas(16) float o_s[4][CDIM];

    // ---- staging: Wq (2/thread), Wv (1/thread), x1 (tid<512), W2 ----
    const float4* W1f4 = (const float4*)W1;
    #pragma unroll
    for (int m = tid; m < 64 * 32; m += 1024) {
        const int c = m >> 5, e4 = m & 31;
        wq_s[c * 32 + (e4 ^ (c & 31))] = W1f4[c * 64 + 32 + e4];
    }
    {
        const int m = tid & 1023;
        if (m < 64 * 16) {
            const int hh = m >> 4, e4 = m & 15;
            wv_s[hh * 16 + (e4 ^ (hh & 15))] = ((const float4*)Wv)[hh * 16 + e4];
        }
    }
    if (tid < 512) {
        const int rp = tid >> 7, d = tid & 127;
        const int i  = r[rp];
        x1s[rp][d] = (d < CDIM) ? pos[i * CDIM + d]
                                : x[(b * TLEN + i) * CDIM + (d - CDIM)];
    }
    if (tid >= 512 && tid < 528) w24_s[tid - 512] = ((const float4*)W2)[tid - 512];
    __syncthreads();

    // ---- hq: (k, part, c) = (tid>>8, (tid>>6)&3, tid&63); 8-f4 dots ----
    {
        const int k = tid >> 8, part = (tid >> 6) & 3, c = tid & 63;
        const float4* xv = ((const float4*)x1s[k]) + part * 8;
        const float4* wb = wq_s + c * 32;
        const int sw = c & 31;
        float4 a = make_float4(0.f, 0.f, 0.f, 0.f);
        #pragma unroll
        for (int d4 = 0; d4 < 8; ++d4) {
            const float4 xx = xv[d4];
            const float4 ww = wb[(part * 8 + d4) ^ sw];
            a.x = fmaf(xx.x, ww.x, a.x); a.y = fmaf(xx.y, ww.y, a.y);
            a.z = fmaf(xx.z, ww.z, a.z); a.w = fmaf(xx.w, ww.w, a.w);
        }
        hqp[k][c][part] = (a.x + a.y) + (a.z + a.w);
    }
    __syncthreads();
    if (tid < 256) {
        const int k = tid >> 6, c = tid & 63;
        hq_sf[k][c] = hqp[k][c][0] + hqp[k][c][1] + hqp[k][c][2]
                    + hqp[k][c][3] + b1[c];
    }
    __syncthreads();

    // ---- scores for this half's 2 rows; wave-uniform causal skip ----
    const float b2v = b2[0];
    const float4* hk4b = hkt4 + b * 16 * TLEN;
    const int wbase = gw << 6;                 // wave's j base within 0..511

    float mw2[2], pt2[2], sw2[2];
    const int myk[2] = { kA, kB };
    #pragma unroll
    for (int q = 0; q < 2; ++q) {
        const int rk = r[myk[q]];
        if (wbase <= rk) {
            const float4* hq4 = (const float4*)hq_sf[myk[q]];
            float4 acc = make_float4(0.f, 0.f, 0.f, 0.f);
            #pragma unroll
            for (int c4 = 0; c4 < 16; ++c4) {
                const float4 kk = hk4b[c4 * TLEN + jj];
                const float4 qq = hq4[c4];
                const float4 w2v = w24_s[c4];
                acc.x = fmaf(fmaxf(kk.x + qq.x, 0.f), w2v.x, acc.x);
                acc.y = fmaf(fmaxf(kk.y + qq.y, 0.f), w2v.y, acc.y);
                acc.z = fmaf(fmaxf(kk.z + qq.z, 0.f), w2v.z, acc.z);
                acc.w = fmaf(fmaxf(kk.w + qq.w, 0.f), w2v.w, acc.w);
            }
            const bool vld = (jj <= rk);
            const float sv = vld ? ((acc.x + acc.y) + (acc.z + acc.w) + b2v)
                                   * 0.125f
                                 : -1e30f;
            float m = sv;
            #pragma unroll
            for (int off = 32; off > 0; off >>= 1)
                m = fmaxf(m, __shfl_xor(m, off));
            mw2[q] = m;
            pt2[q] = vld ? __expf(sv - m) : 0.f;
            float sm = pt2[q];
            #pragma unroll
            for (int off = 32; off > 0; off >>= 1)
                sm += __shfl_xor(sm, off);
            sw2[q] = sm;
        } else {
            mw2[q] = -1e30f; pt2[q] = 0.f; sw2[q] = 0.f;
        }
    }
    if ((tid & 63) == 0) {
        wredm[wg] = make_float2(mw2[0], mw2[1]);
        wreds[wg] = make_float2(sw2[0], sw2[1]);
    }
    __syncthreads();

    {   // combine this half's 8 wave-entries
        const int base = half * 8;
        float gmA = -1e30f, gmB = -1e30f;
        #pragma unroll
        for (int ww = 0; ww < 8; ++ww) {
            const float2 rm = wredm[base + ww];
            gmA = fmaxf(gmA, rm.x);
            gmB = fmaxf(gmB, rm.y);
        }
        float gsA = 0.f, gsB = 0.f;
        #pragma unroll
        for (int ww = 0; ww < 8; ++ww) {
            const float2 rm = wredm[base + ww];
            const float2 rs = wreds[base + ww];
            gsA = fmaf(rs.x, __expf(rm.x - gmA), gsA);
            gsB = fmaf(rs.y, __expf(rm.y - gmB), gsB);
        }
        pS[kA][jj] = pt2[0] * (__expf(mw2[0] - gmA) / gsA);
        pS[kB][jj] = pt2[1] * (__expf(mw2[1] - gmB) / gsB);
    }
    __syncthreads();

    // ---- PV for this half's 2 rows; shared x loads within half ----
    const int h = tid & 63;
    const float* xh = x + b * TLEN * CDIM + h;
    // long row of the half: half0 -> r[3], half1 -> r[2]; both > short row
    const int rkA = r[kA], rkB = r[kB];
    const int nj4 = (rkB >> 2) + 1;
    float4 aA = make_float4(0.f, 0.f, 0.f, 0.f);
    float4 aB = aA;
    for (int j4 = gw; j4 < nj4; j4 += 8) {
        const int j0 = j4 * 4;
        const float4 pB4 = ((const float4*)pS[kB])[j4];
        const float x0 = xh[j0 * CDIM];
        const float x1 = xh[(j0 + 1) * CDIM];
        const float x2 = xh[(j0 + 2) * CDIM];
        const float x3 = xh[(j0 + 3) * CDIM];
        aB.x = fmaf(pB4.x, x0, aB.x); aB.y = fmaf(pB4.y, x1, aB.y);
        aB.z = fmaf(pB4.z, x2, aB.z); aB.w = fmaf(pB4.w, x3, aB.w);
        if (j0 <= rkA) {                               // wave-uniform
            const float4 pA4 = ((const float4*)pS[kA])[j4];
            aA.x = fmaf(pA4.x, x0, aA.x); aA.y = fmaf(pA4.y, x1, aA.y);
            aA.z = fmaf(pA4.z, x2, aA.z); aA.w = fmaf(pA4.w, x3, aA.w);
        }
    }
    pvs[kA][gw][h] = (aA.x + aA.y) + (aA.z + aA.w);
    pvs[kB][gw][h] = (aB.x + aB.y) + (aB.z + aB.w);
    __syncthreads();
    if (tid < 256) {
        const int k = tid >> 6, hh = tid & 63;
        float o = pvs[k][0][hh];
        #pragma unroll
        for (int ww = 1; ww < 8; ++ww) o += pvs[k][ww][hh];
        o_s[k][hh] = o;
    }
    __syncthreads();
    if (tid < 256) {                           // out = o_k . Wv[h,:] (LDS)
        const int k = tid >> 6, hh = tid & 63;
        const float4* wb = wv_s + hh * 16;
        const int sw = hh & 15;
        const float4* o4 = (const float4*)o_s[k];
        float4 a = make_float4(0.f, 0.f, 0.f, 0.f);
        #pragma unroll
        for (int c4 = 0; c4 < 16; ++c4) {
            const float4 wwv = wb[c4 ^ sw];
            const float4 oo = o4[c4];
            a.x = fmaf(oo.x, wwv.x, a.x); a.y = fmaf(oo.y, wwv.y, a.y);
            a.z = fmaf(oo.z, wwv.z, a.z); a.w = fmaf(oo.w, wwv.w, a.w);
        }
        out[(b * TLEN + r[k]) * CDIM + hh] = (a.x + a.y) + (a.z + a.w);
    }
}

extern "C" void kernel_launch(void* const* d_in, const int* in_sizes, int n_in,
                              void* d_out, int out_size, void* d_ws, size_t ws_size,
                              hipStream_t stream)
{
    const float* x   = (const float*)d_in[0];
    const float* pos = (const float*)d_in[1];
    const float* W1  = (const float*)d_in[2];
    const float* b1  = (const float*)d_in[3];
    const float* W2  = (const float*)d_in[4];
    const float* b2  = (const float*)d_in[5];
    const float* Wv  = (const float*)d_in[6];
    float* out = (float*)d_out;

    float4* hkt4 = (float4*)d_ws;              // 256 KiB transposed hk

    hk_kernel<<<BDIM * TLEN / 4, 256, 0, stream>>>(x, pos, W1, hkt4);
    attn_kernel<<<BDIM * TLEN / 4, 1024, 0, stream>>>(x, pos, W1, b1, W2, b2, Wv,
                                                      hkt4, out);
}